// Round 9
// baseline (210.432 us; speedup 1.0000x reference)
//
#include <hip/hip_runtime.h>
#include <hip/hip_bf16.h>
#include <math.h>

// Problem constants
#define B_   8
#define C_   512
#define NH_  8
#define HD_  64
#define NSP  1024            // H*W
#define M_   (B_*NSP)        // 8192 rows
#define NQKV 1536
#define SCALE_ 0.125f        // 1/sqrt(64)
#define S2L_  0.18033688f    // SCALE_ * log2(e)

typedef __attribute__((ext_vector_type(8))) __bf16 bf16x8;
typedef __attribute__((ext_vector_type(4))) float  f32x4;

__device__ __forceinline__ unsigned short f2bf(float f) {
  unsigned int u = __float_as_uint(f);
  u = u + 0x7fffu + ((u >> 16) & 1u);   // round-to-nearest-even
  return (unsigned short)(u >> 16);
}

// packed f32x2 -> bf16x2 (v_cvt_pk_bf16_f32 on gfx950); a -> low 16
__device__ __forceinline__ unsigned int pk2bf(float a, float b) {
  __hip_bfloat162 t = __float22bfloat162_rn(make_float2(a, b));
  unsigned int u; __builtin_memcpy(&u, &t, 4);
  return u;
}

// async global->LDS 16B (dest = wave-uniform base + lane*16)
__device__ __forceinline__ void async16(const unsigned short* g, unsigned short* l) {
  __builtin_amdgcn_global_load_lds(
      (const __attribute__((address_space(1))) void*)g,
      (__attribute__((address_space(3))) void*)l, 16, 0, 0);
}

// ------------------------------------------------ LN stats (partial sums)
// 1024 blocks = (b, n-chunk of 32, c-quarter); psum[cg][b*N+n], psum2 same.
// 4x the blocks of the old version -> 16-deep load loop instead of 64.
__global__ void ln_stats_kernel(const float* __restrict__ x,
                                float* __restrict__ psum,
                                float* __restrict__ psum2) {
  int tx = threadIdx.x & 31, ty = threadIdx.x >> 5;
  int cg  = blockIdx.x & 3;
  int nch = (blockIdx.x >> 2) & 31;
  int b   = blockIdx.x >> 7;
  int n0 = nch * 32;
  const float* xp = x + (size_t)b * C_ * NSP + n0 + tx;
  float s = 0.f, s2 = 0.f;
  for (int c = cg * 128 + ty; c < cg * 128 + 128; c += 8) {
    float v = xp[(size_t)c * NSP];
    s += v; s2 += v * v;
  }
  __shared__ float sh_s[8][32], sh_s2[8][32];
  sh_s[ty][tx] = s; sh_s2[ty][tx] = s2;
  __syncthreads();
  if (ty == 0) {
    float S = 0.f, S2 = 0.f;
    for (int j = 0; j < 8; j++) { S += sh_s[j][tx]; S2 += sh_s2[j][tx]; }
    psum [cg * M_ + b * NSP + n0 + tx] = S;
    psum2[cg * M_ + b * NSP + n0 + tx] = S2;
  }
}

// --------------- LN apply+transpose (blocks 0..1023) + tiled weight convert
// blocks [0,1024):     apply (c0=(bx&7)*64, n0=((bx>>3)&15)*64, b=bx>>7)
// blocks [1024,1216):  wqkv 64x64 transpose tiles (8k x 24n)
// blocks [1216,1280):  wproj 64x64 transpose tiles (8k x 8n)
__global__ __launch_bounds__(256) void applyw_kernel(
    const float* __restrict__ x, const float* __restrict__ psum,
    const float* __restrict__ psum2, const float* __restrict__ gamma,
    const float* __restrict__ beta, const float* __restrict__ wqkv,
    const float* __restrict__ wproj, unsigned short* __restrict__ xn,
    unsigned short* __restrict__ wqkvT, unsigned short* __restrict__ wprojT) {
  int tid = threadIdx.x;
  __shared__ float tile[64][65];
  int tx = tid & 63, ty = tid >> 6;
  if (blockIdx.x >= 1024) {
    // weight transpose via LDS bounce: in [k][n] fp32 -> out [n][k] bf16
    const float* W; unsigned short* WT; int NW, t;
    if (blockIdx.x < 1216) { W = wqkv;  WT = wqkvT;  NW = NQKV; t = blockIdx.x - 1024; }
    else                   { W = wproj; WT = wprojT; NW = C_;   t = blockIdx.x - 1216; }
    int ntiles = NW >> 6;
    int kt = t / ntiles, nt = t - kt * ntiles;
    for (int i = ty; i < 64; i += 4)                      // read coalesced in n
      tile[i][tx] = W[(size_t)(kt * 64 + i) * NW + nt * 64 + tx];
    __syncthreads();
    for (int i = ty; i < 64; i += 4)                      // write rows of WT
      WT[(size_t)(nt * 64 + i) * C_ + kt * 64 + tx] = f2bf(tile[tx][i]);
    return;
  }
  __shared__ float smu[64], srs[64];
  int c0 = (blockIdx.x & 7) * 64;
  int n0 = ((blockIdx.x >> 3) & 15) * 64;
  int b  = blockIdx.x >> 7;
  if (tid < 64) {                       // reduce 4 partials -> mu, rstd
    int n = b * NSP + n0 + tid;
    float s  = psum [n] + psum [M_ + n] + psum [2 * M_ + n] + psum [3 * M_ + n];
    float s2 = psum2[n] + psum2[M_ + n] + psum2[2 * M_ + n] + psum2[3 * M_ + n];
    float mu = s * (1.0f / C_);
    float var = s2 * (1.0f / C_) - mu * mu;
    smu[tid] = mu;
    srs[tid] = rsqrtf(var + 1e-5f);
  }
  const float* xp = x + ((size_t)b * C_ + c0) * NSP + n0;
  for (int i = ty; i < 64; i += 4)
    tile[i][tx] = xp[(size_t)i * NSP + tx];           // tile[c][n], coalesced
  __syncthreads();
  float g = gamma[c0 + tx], be = beta[c0 + tx];       // tx = c-offset now
  unsigned short* op = xn + ((size_t)(b * NSP + n0)) * C_ + c0 + tx;
  for (int i = ty; i < 64; i += 4) {                  // i = n-offset
    float v = (tile[tx][i] - smu[i]) * srs[i] * g + be;
    op[(size_t)i * C_] = f2bf(v);                     // coalesced bf16 write
  }
}

// ------------------------------------------------------------- QKV GEMM
// C[M,1536] = A[M,512] @ B + bias. 128x128 tiles, global_load_lds width-16,
// single-barrier double-buffered K-loop: barrier drains the prefetch issued
// a full compute-phase earlier (not the just-issued one).
// col<512 -> Q scaled by S2L_; col in [512,1024) -> K; both bf16 stride 1024.
// col>=1024 -> V bf16 transposed into out1 = vt[(b*512+c-1024)*1024+n]
__global__ __launch_bounds__(256) void gemm_qkv_kernel(
    const unsigned short* __restrict__ A,
    const unsigned short* __restrict__ Bt,
    const float* __restrict__ bias,
    unsigned short* __restrict__ out0, unsigned short* __restrict__ out1) {
  __shared__ __align__(16) char smem[32768];   // [2] x (As 8K + Bs 8K)
  int tid = threadIdx.x;
  int wave = tid >> 6, lane = tid & 63, quad = lane >> 4, l15 = lane & 15;
  int n0 = blockIdx.x * 128, m0 = blockIdx.y * 128;
  int mrow = (wave >> 1) * 64, ncol = (wave & 1) * 64;
  int srow = lane >> 2, schunk = (lane & 3) * 8;
  auto stage = [&](int k0, int buf) {
    unsigned short* As = (unsigned short*)(smem + buf * 16384);
    unsigned short* Bs = (unsigned short*)(smem + buf * 16384 + 8192);
#pragma unroll
    for (int j = 0; j < 2; j++) {
      int r0 = (wave + 4 * j) * 16;
      async16(A + (size_t)(m0 + r0 + srow) * 512 + k0 + schunk, As + r0 * 32 + lane * 8);
      async16(Bt + (size_t)(n0 + r0 + srow) * 512 + k0 + schunk, Bs + r0 * 32 + lane * 8);
    }
  };
  f32x4 acc[4][4] = {};
  stage(0, 0);
  for (int kt = 0; kt < 16; kt++) {
    int cur = kt & 1;
    __syncthreads();                 // buf[cur] prefetch (issued last iter) drained
    if (kt < 15) stage((kt + 1) * 32, cur ^ 1);
    unsigned short* As = (unsigned short*)(smem + cur * 16384);
    unsigned short* Bs = (unsigned short*)(smem + cur * 16384 + 8192);
    bf16x8 a[4], bb[4];
#pragma unroll
    for (int mt = 0; mt < 4; mt++)
      a[mt] = *(const bf16x8*)(As + (mrow + mt * 16 + l15) * 32 + quad * 8);
#pragma unroll
    for (int nt = 0; nt < 4; nt++)
      bb[nt] = *(const bf16x8*)(Bs + (ncol + nt * 16 + l15) * 32 + quad * 8);
#pragma unroll
    for (int mt = 0; mt < 4; mt++)
#pragma unroll
      for (int nt = 0; nt < 4; nt++)
        acc[mt][nt] = __builtin_amdgcn_mfma_f32_16x16x32_bf16(
            a[mt], bb[nt], acc[mt][nt], 0, 0, 0);
  }
  if (n0 < 1024) {
    float sc = ((n0 + ncol) < 512) ? S2L_ : 1.0f;   // pre-scale Q for exp2 softmax
#pragma unroll
    for (int mt = 0; mt < 4; mt++)
#pragma unroll
      for (int nt = 0; nt < 4; nt++)
#pragma unroll
        for (int r = 0; r < 4; r++) {
          int row = m0 + mrow + mt * 16 + quad * 4 + r;
          int col = n0 + ncol + nt * 16 + l15;
          out0[(size_t)row * 1024 + col] = f2bf((acc[mt][nt][r] + bias[col]) * sc);
        }
  } else {
    // V blocks: bf16 transposed into vt[(b*512 + (col-1024))*1024 + n]
    __syncthreads();
    unsigned short* buf = (unsigned short*)smem + wave * (64 * 17);
    int b = m0 >> 10, nbase = m0 & 1023;
    for (int nc = 0; nc < 4; nc++) {
#pragma unroll
      for (int mt = 0; mt < 4; mt++)
#pragma unroll
        for (int r = 0; r < 4; r++) {
          int col = n0 + ncol + nc * 16 + l15;
          buf[(mt * 16 + quad * 4 + r) * 17 + l15] = f2bf(acc[mt][nc][r] + bias[col]);
        }
      __syncthreads();
      for (int cc = 0; cc < 16; cc++) {
        int crel = n0 - 1024 + ncol + nc * 16 + cc;
        out1[((size_t)b * C_ + crel) * NSP + nbase + mrow + lane] = buf[lane * 17 + cc];
      }
      __syncthreads();
    }
  }
}

// ------------------------------------------------------------- proj GEMM
// out[b][c][n] fp32 = (A[M,512] @ Bt^T + bias)^T. 64x128 (MxN) tiles ->
// 512 blocks (2/CU). Single-barrier double-buffered K-loop as qkv.
__global__ __launch_bounds__(256) void gemm_proj_kernel(
    const unsigned short* __restrict__ A,
    const unsigned short* __restrict__ Bt,
    const float* __restrict__ bias,
    float* __restrict__ O) {
  __shared__ __align__(16) char smem[24576];   // [2] x (As 4K + Bs 8K)
  int tid = threadIdx.x;
  int wave = tid >> 6, lane = tid & 63, quad = lane >> 4, l15 = lane & 15;
  int n0 = blockIdx.x * 128, m0 = blockIdx.y * 64;
  int wm0 = (wave >> 1) * 32, wc0 = (wave & 1) * 64;
  int srow = lane >> 2, schunk = (lane & 3) * 8;
  auto stage = [&](int k0, int buf) {
    unsigned short* As = (unsigned short*)(smem + buf * 12288);
    unsigned short* Bs = (unsigned short*)(smem + buf * 12288 + 4096);
    async16(A + (size_t)(m0 + wave * 16 + srow) * 512 + k0 + schunk,
            As + (wave * 16) * 32 + lane * 8);
#pragma unroll
    for (int j = 0; j < 2; j++) {
      int r0 = (wave + 4 * j) * 16;
      async16(Bt + (size_t)(n0 + r0 + srow) * 512 + k0 + schunk, Bs + r0 * 32 + lane * 8);
    }
  };
  f32x4 acc[2][4] = {};
  stage(0, 0);
  for (int kt = 0; kt < 16; kt++) {
    int cur = kt & 1;
    __syncthreads();
    if (kt < 15) stage((kt + 1) * 32, cur ^ 1);
    unsigned short* As = (unsigned short*)(smem + cur * 12288);
    unsigned short* Bs = (unsigned short*)(smem + cur * 12288 + 4096);
    bf16x8 a[2], bb[4];
#pragma unroll
    for (int mt = 0; mt < 2; mt++)
      a[mt] = *(const bf16x8*)(As + (wm0 + mt * 16 + l15) * 32 + quad * 8);
#pragma unroll
    for (int nt = 0; nt < 4; nt++)
      bb[nt] = *(const bf16x8*)(Bs + (wc0 + nt * 16 + l15) * 32 + quad * 8);
#pragma unroll
    for (int mt = 0; mt < 2; mt++)
#pragma unroll
      for (int nt = 0; nt < 4; nt++)
        acc[mt][nt] = __builtin_amdgcn_mfma_f32_16x16x32_bf16(
            a[mt], bb[nt], acc[mt][nt], 0, 0, 0);
  }
  __syncthreads();                        // all waves done reading tiles
  float* buf = (float*)smem + wave * (32 * 17);   // [32][17] per wave
  int b = m0 >> 10, nbase = m0 & 1023;
  for (int nc = 0; nc < 4; nc++) {
#pragma unroll
    for (int mt = 0; mt < 2; mt++)
#pragma unroll
      for (int r = 0; r < 4; r++) {
        int col = n0 + wc0 + nc * 16 + l15;
        buf[(mt * 16 + quad * 4 + r) * 17 + l15] = acc[mt][nc][r] + bias[col];
      }
    // wave-private: ds_write->ds_read ordering handled by lgkmcnt, no barrier
#pragma unroll
    for (int j = 0; j < 8; j++) {
      int cl = j * 2 + (lane >> 5);       // 0..15 within nc group
      int ml = lane & 31;
      int c = n0 + wc0 + nc * 16 + cl;
      O[((size_t)b * C_ + c) * NSP + nbase + wm0 + ml] = buf[ml * 17 + cl];
    }
  }
}

// ------------------------------------------------------- flash attention
// qk: [b*n][1024] bf16 (Q cols 0-511 PRE-SCALED by S2L_, K cols 512-1023);
// vt: [b*512+h*64+d][n]. block = (b,h, 64 q-rows), 4 waves:
//   qw = wave&1 (q-half, 32 rows), kh = wave>>1 (KEY-half, 512 keys).
// No-max exp2 softmax additive over keys -> key-parallel waves, in-block
// (O,l) combine. NEXT tile is prefetched into REGISTERS (static uint4[4],
// no dynamic indexing -> no spill) at iter top, ds_written to LDS after the
// read-barrier: global latency rides the compute phase instead of a barrier.
// Tiles unpadded [64][64] + XOR chunk swizzle (measured conflict-free).
__global__ __launch_bounds__(256, 3) void attn_kernel(
    const unsigned short* __restrict__ qk,
    const unsigned short* __restrict__ vt,
    unsigned short* __restrict__ o_ws) {
  __shared__ __align__(16) unsigned short Ks[2][64][64];   // [kh][key][d]
  __shared__ __align__(16) unsigned short Vts[2][64][64];  // [kh][d][key]
  __shared__ __align__(16) unsigned short Ps[4][32][68];   // per-wave P[m][n]
  int tid = threadIdx.x;
  int wave = tid >> 6, lane = tid & 63, quad = lane >> 4, l15 = lane & 15;
  int qw = wave & 1, kh = wave >> 1;
  int b = blockIdx.x >> 3, h = blockIdx.x & 7;
  int q0 = blockIdx.y * 64 + qw * 32;
  int srow = lane >> 3, scc = lane & 7, swz = scc ^ srow;
  // ones A-fragment for l-sum MFMA: A[0][k]=1 else 0  (row = l15)
  uint4 ones4 = (l15 == 0) ? make_uint4(0x3F803F80u, 0x3F803F80u, 0x3F803F80u, 0x3F803F80u)
                           : make_uint4(0u, 0u, 0u, 0u);
  bf16x8 av5; __builtin_memcpy(&av5, &ones4, 16);
  // Q fragments straight from global (B-operand layout: rows m, k=d)
  bf16x8 bq[2][2];
#pragma unroll
  for (int mt = 0; mt < 2; mt++)
#pragma unroll
    for (int ks = 0; ks < 2; ks++)
      bq[mt][ks] = *(const bf16x8*)(
          qk + (size_t)(b * NSP + q0 + mt * 16 + l15) * 1024 +
          h * 64 + ks * 32 + quad * 8);
  // prologue: async-stage tile it=0 of this kh half
#pragma unroll
  for (int g = 0; g < 4; g++) {
    int row = qw * 32 + g * 8;
    async16(qk + (size_t)(b * NSP + kh * 512 + row + srow) * 1024 + 512 + h * 64 + swz * 8,
            &Ks[kh][row][0]);
    async16(vt + ((size_t)(b * C_ + h * 64 + row + srow)) * NSP + kh * 512 + swz * 8,
            &Vts[kh][row][0]);
  }
  f32x4 ot[4][2] = {};     // O^T partial: [d = dt*16+quad*4+r][m = mt*16+l15]
  f32x4 lacc[2] = {};      // l partial in lacc[mt][0] on quad==0 lanes
  __syncthreads();         // drains prologue async (+ Q/ones reg loads)
  for (int it = 0; it < 8; it++) {
    // prefetch NEXT tile into registers; lands during compute below
    uint4 kr[4], vr[4];
    if (it < 7) {
      int k0n = kh * 512 + (it + 1) * 64;
#pragma unroll
      for (int g = 0; g < 4; g++) {
        int row = qw * 32 + g * 8 + srow;
        kr[g] = *(const uint4*)(qk + (size_t)(b * NSP + k0n + row) * 1024 + 512 + h * 64 + swz * 8);
        vr[g] = *(const uint4*)(vt + ((size_t)(b * C_ + h * 64 + row)) * NSP + k0n + swz * 8);
      }
    }
    // S^T[n][m] = mfma(A=K rows n, B=Q rows m)
    bf16x8 ak[4][2];
#pragma unroll
    for (int n4 = 0; n4 < 4; n4++)
#pragma unroll
      for (int ks = 0; ks < 2; ks++)
        ak[n4][ks] = *(const bf16x8*)(
            &Ks[kh][n4 * 16 + l15][((ks * 4 + quad) ^ (l15 & 7)) * 8]);
    f32x4 s[4][2] = {};
#pragma unroll
    for (int n4 = 0; n4 < 4; n4++)
#pragma unroll
      for (int mt = 0; mt < 2; mt++)
#pragma unroll
        for (int ks = 0; ks < 2; ks++)
          s[n4][mt] = __builtin_amdgcn_mfma_f32_16x16x32_bf16(
              ak[n4][ks], bq[mt][ks], s[n4][mt], 0, 0, 0);
    // P = exp2(S) (no max), packed cvt, wave-private LDS spill
#pragma unroll
    for (int mt = 0; mt < 2; mt++)
#pragma unroll
      for (int n4 = 0; n4 < 4; n4++) {
        float p0 = __builtin_amdgcn_exp2f(s[n4][mt][0]);
        float p1 = __builtin_amdgcn_exp2f(s[n4][mt][1]);
        float p2 = __builtin_amdgcn_exp2f(s[n4][mt][2]);
        float p3 = __builtin_amdgcn_exp2f(s[n4][mt][3]);
        *(uint2*)(&Ps[wave][mt * 16 + l15][n4 * 16 + quad * 4]) =
            make_uint2(pk2bf(p0, p1), pk2bf(p2, p3));
      }
    // O^T += mfma(A=V^T rows d, B=P rows m); l += ones-row MFMA
    bf16x8 av[4][2], bp[2][2];
#pragma unroll
    for (int dt = 0; dt < 4; dt++)
#pragma unroll
      for (int ks = 0; ks < 2; ks++)
        av[dt][ks] = *(const bf16x8*)(
            &Vts[kh][dt * 16 + l15][((ks * 4 + quad) ^ (l15 & 7)) * 8]);
#pragma unroll
    for (int mt = 0; mt < 2; mt++)
#pragma unroll
      for (int ks = 0; ks < 2; ks++)
        bp[mt][ks] = *(const bf16x8*)(&Ps[wave][mt * 16 + l15][ks * 32 + quad * 8]);
#pragma unroll
    for (int dt = 0; dt < 4; dt++)
#pragma unroll
      for (int mt = 0; mt < 2; mt++)
#pragma unroll
        for (int ks = 0; ks < 2; ks++)
          ot[dt][mt] = __builtin_amdgcn_mfma_f32_16x16x32_bf16(
              av[dt][ks], bp[mt][ks], ot[dt][mt], 0, 0, 0);
#pragma unroll
    for (int mt = 0; mt < 2; mt++)
#pragma unroll
      for (int ks = 0; ks < 2; ks++)
        lacc[mt] = __builtin_amdgcn_mfma_f32_16x16x32_bf16(
            av5, bp[mt][ks], lacc[mt], 0, 0, 0);
    if (it < 7) {
      __syncthreads();               // all waves done reading tile it
#pragma unroll
      for (int g = 0; g < 4; g++) {  // regs -> LDS (same cells async16 used)
        int row = qw * 32 + g * 8 + srow;
        *(uint4*)(&Ks[kh][row][scc * 8]) = kr[g];
        *(uint4*)(&Vts[kh][row][scc * 8]) = vr[g];
      }
      __syncthreads();               // tile it+1 visible to both qw waves
    }
  }
  // in-block combine across key-halves (tiles dead -> alias as fp32 buffers)
  float* Cb = (float*)&Ks[0][0][0];   // [2][16][68] floats (qw, l15, d)
  float* Lb = (float*)&Vts[0][0][0];  // [2][16] floats
#pragma unroll
  for (int mt = 0; mt < 2; mt++) {
    __syncthreads();
    if (kh == 1) {
#pragma unroll
      for (int dt = 0; dt < 4; dt++)
        *(f32x4*)&Cb[(qw * 16 + l15) * 68 + dt * 16 + quad * 4] = ot[dt][mt];
      if (quad == 0) Lb[qw * 16 + l15] = lacc[mt][0];
    }
    __syncthreads();
    if (kh == 0) {
#pragma unroll
      for (int dt = 0; dt < 4; dt++)
        ot[dt][mt] += *(const f32x4*)&Cb[(qw * 16 + l15) * 68 + dt * 16 + quad * 4];
      float lsum = lacc[mt][0] + Lb[qw * 16 + l15];   // valid on quad==0
      float lv = __shfl(lsum, l15);                   // broadcast from quad0
      float inv = 1.f / lv;
      size_t rowoff = (size_t)(b * NSP + q0 + mt * 16 + l15) * 512 + h * 64;
#pragma unroll
      for (int dt = 0; dt < 4; dt++)
        *(uint2*)(o_ws + rowoff + dt * 16 + quad * 4) =
            make_uint2(pk2bf(ot[dt][mt][0] * inv, ot[dt][mt][1] * inv),
                       pk2bf(ot[dt][mt][2] * inv, ot[dt][mt][3] * inv));
    }
  }
}

// ------------------------------------------------------------------ launch
extern "C" void kernel_launch(void* const* d_in, const int* in_sizes, int n_in,
                              void* d_out, int out_size, void* d_ws, size_t ws_size,
                              hipStream_t stream) {
  const float* x     = (const float*)d_in[0];
  const float* gamma = (const float*)d_in[1];
  const float* beta  = (const float*)d_in[2];
  const float* wqkv  = (const float*)d_in[3];
  const float* bqkv  = (const float*)d_in[4];
  const float* wproj = (const float*)d_in[5];
  const float* bproj = (const float*)d_in[6];
  char* ws = (char*)d_ws;
  // workspace layout (~36 MB; o_bf aliases xn_bf — xn dead after QKV GEMM)
  float*          psum   = (float*)ws;                        // 128 KB [4][8192]
  float*          psum2  = (float*)(ws + 131072);             // 128 KB
  unsigned short* wqkvT  = (unsigned short*)(ws + 262144);    // 1.5 MB
  unsigned short* wprojT = (unsigned short*)(ws + 1835008);   // 0.5 MB
  unsigned short* qk_bf  = (unsigned short*)(ws + 2359296);   //  16 MB [m][1024]
  unsigned short* vt_bf  = (unsigned short*)(ws + 19136512);  //   8 MB [b*512+c][n]
  unsigned short* xn_bf  = (unsigned short*)(ws + 27525120);  //   8 MB
  unsigned short* o_bf   = xn_bf;                             //   8 MB (alias)
  float* out = (float*)d_out;

  ln_stats_kernel<<<1024, 256, 0, stream>>>(x, psum, psum2);
  applyw_kernel<<<1024 + 192 + 64, 256, 0, stream>>>(x, psum, psum2, gamma, beta,
                                                     wqkv, wproj, xn_bf, wqkvT, wprojT);
  gemm_qkv_kernel<<<dim3(NQKV / 128, M_ / 128), 256, 0, stream>>>(
      xn_bf, wqkvT, bqkv, qk_bf, vt_bf);
  attn_kernel<<<dim3(B_ * NH_, NSP / 64), 256, 0, stream>>>(qk_bf, vt_bf, o_bf);
  gemm_proj_kernel<<<dim3(C_ / 128, M_ / 64), 256, 0, stream>>>(
      o_bf, wprojT, bproj, out);
}

// Round 10
// 158.234 us; speedup vs baseline: 1.3299x; 1.3299x over previous
//
#include <hip/hip_runtime.h>
#include <hip/hip_bf16.h>
#include <math.h>

// Problem constants
#define B_   8
#define C_   512
#define NH_  8
#define HD_  64
#define NSP  1024            // H*W
#define M_   (B_*NSP)        // 8192 rows
#define NQKV 1536
#define SCALE_ 0.125f        // 1/sqrt(64)
#define S2L_  0.18033688f    // SCALE_ * log2(e)

typedef __attribute__((ext_vector_type(8))) __bf16 bf16x8;
typedef __attribute__((ext_vector_type(4))) float  f32x4;

__device__ __forceinline__ unsigned short f2bf(float f) {
  unsigned int u = __float_as_uint(f);
  u = u + 0x7fffu + ((u >> 16) & 1u);   // round-to-nearest-even
  return (unsigned short)(u >> 16);
}

// packed f32x2 -> bf16x2 (v_cvt_pk_bf16_f32 on gfx950); a -> low 16
__device__ __forceinline__ unsigned int pk2bf(float a, float b) {
  __hip_bfloat162 t = __float22bfloat162_rn(make_float2(a, b));
  unsigned int u; __builtin_memcpy(&u, &t, 4);
  return u;
}

// async global->LDS 16B (dest = wave-uniform base + lane*16)
__device__ __forceinline__ void async16(const unsigned short* g, unsigned short* l) {
  __builtin_amdgcn_global_load_lds(
      (const __attribute__((address_space(1))) void*)g,
      (__attribute__((address_space(3))) void*)l, 16, 0, 0);
}

// ------------------------------------------------ LN stats (partial sums)
// 1024 blocks = (b, n-chunk of 32, c-quarter); psum[cg][b*N+n], psum2 same.
__global__ void ln_stats_kernel(const float* __restrict__ x,
                                float* __restrict__ psum,
                                float* __restrict__ psum2) {
  int tx = threadIdx.x & 31, ty = threadIdx.x >> 5;
  int cg  = blockIdx.x & 3;
  int nch = (blockIdx.x >> 2) & 31;
  int b   = blockIdx.x >> 7;
  int n0 = nch * 32;
  const float* xp = x + (size_t)b * C_ * NSP + n0 + tx;
  float s = 0.f, s2 = 0.f;
  for (int c = cg * 128 + ty; c < cg * 128 + 128; c += 8) {
    float v = xp[(size_t)c * NSP];
    s += v; s2 += v * v;
  }
  __shared__ float sh_s[8][32], sh_s2[8][32];
  sh_s[ty][tx] = s; sh_s2[ty][tx] = s2;
  __syncthreads();
  if (ty == 0) {
    float S = 0.f, S2 = 0.f;
    for (int j = 0; j < 8; j++) { S += sh_s[j][tx]; S2 += sh_s2[j][tx]; }
    psum [cg * M_ + b * NSP + n0 + tx] = S;
    psum2[cg * M_ + b * NSP + n0 + tx] = S2;
  }
}

// --------------- LN apply+transpose (blocks 0..1023) + tiled weight convert
// blocks [0,1024):     apply (c0=(bx&7)*64, n0=((bx>>3)&15)*64, b=bx>>7)
// blocks [1024,1216):  wqkv 64x64 transpose tiles (8k x 24n)
// blocks [1216,1280):  wproj 64x64 transpose tiles (8k x 8n)
__global__ __launch_bounds__(256) void applyw_kernel(
    const float* __restrict__ x, const float* __restrict__ psum,
    const float* __restrict__ psum2, const float* __restrict__ gamma,
    const float* __restrict__ beta, const float* __restrict__ wqkv,
    const float* __restrict__ wproj, unsigned short* __restrict__ xn,
    unsigned short* __restrict__ wqkvT, unsigned short* __restrict__ wprojT) {
  int tid = threadIdx.x;
  __shared__ float tile[64][65];
  int tx = tid & 63, ty = tid >> 6;
  if (blockIdx.x >= 1024) {
    // weight transpose via LDS bounce: in [k][n] fp32 -> out [n][k] bf16
    const float* W; unsigned short* WT; int NW, t;
    if (blockIdx.x < 1216) { W = wqkv;  WT = wqkvT;  NW = NQKV; t = blockIdx.x - 1024; }
    else                   { W = wproj; WT = wprojT; NW = C_;   t = blockIdx.x - 1216; }
    int ntiles = NW >> 6;
    int kt = t / ntiles, nt = t - kt * ntiles;
    for (int i = ty; i < 64; i += 4)                      // read coalesced in n
      tile[i][tx] = W[(size_t)(kt * 64 + i) * NW + nt * 64 + tx];
    __syncthreads();
    for (int i = ty; i < 64; i += 4)                      // write rows of WT
      WT[(size_t)(nt * 64 + i) * C_ + kt * 64 + tx] = f2bf(tile[tx][i]);
    return;
  }
  __shared__ float smu[64], srs[64];
  int c0 = (blockIdx.x & 7) * 64;
  int n0 = ((blockIdx.x >> 3) & 15) * 64;
  int b  = blockIdx.x >> 7;
  if (tid < 64) {                       // reduce 4 partials -> mu, rstd
    int n = b * NSP + n0 + tid;
    float s  = psum [n] + psum [M_ + n] + psum [2 * M_ + n] + psum [3 * M_ + n];
    float s2 = psum2[n] + psum2[M_ + n] + psum2[2 * M_ + n] + psum2[3 * M_ + n];
    float mu = s * (1.0f / C_);
    float var = s2 * (1.0f / C_) - mu * mu;
    smu[tid] = mu;
    srs[tid] = rsqrtf(var + 1e-5f);
  }
  const float* xp = x + ((size_t)b * C_ + c0) * NSP + n0;
  for (int i = ty; i < 64; i += 4)
    tile[i][tx] = xp[(size_t)i * NSP + tx];           // tile[c][n], coalesced
  __syncthreads();
  float g = gamma[c0 + tx], be = beta[c0 + tx];       // tx = c-offset now
  unsigned short* op = xn + ((size_t)(b * NSP + n0)) * C_ + c0 + tx;
  for (int i = ty; i < 64; i += 4) {                  // i = n-offset
    float v = (tile[tx][i] - smu[i]) * srs[i] * g + be;
    op[(size_t)i * C_] = f2bf(v);                     // coalesced bf16 write
  }
}

// ------------------------------------------------------------- QKV GEMM
// C[M,1536] = A[M,512] @ B + bias. 128x128 tiles, global_load_lds width-16,
// single-barrier double-buffered K-loop (barrier drains the prefetch issued
// a full compute-phase earlier).
// col<512 -> Q scaled by S2L_; col in [512,1024) -> K; both bf16 stride 1024.
// col>=1024 -> V bf16 transposed into out1 = vt[(b*512+c-1024)*1024+n]
__global__ __launch_bounds__(256) void gemm_qkv_kernel(
    const unsigned short* __restrict__ A,
    const unsigned short* __restrict__ Bt,
    const float* __restrict__ bias,
    unsigned short* __restrict__ out0, unsigned short* __restrict__ out1) {
  __shared__ __align__(16) char smem[32768];   // [2] x (As 8K + Bs 8K)
  int tid = threadIdx.x;
  int wave = tid >> 6, lane = tid & 63, quad = lane >> 4, l15 = lane & 15;
  int n0 = blockIdx.x * 128, m0 = blockIdx.y * 128;
  int mrow = (wave >> 1) * 64, ncol = (wave & 1) * 64;
  int srow = lane >> 2, schunk = (lane & 3) * 8;
  auto stage = [&](int k0, int buf) {
    unsigned short* As = (unsigned short*)(smem + buf * 16384);
    unsigned short* Bs = (unsigned short*)(smem + buf * 16384 + 8192);
#pragma unroll
    for (int j = 0; j < 2; j++) {
      int r0 = (wave + 4 * j) * 16;
      async16(A + (size_t)(m0 + r0 + srow) * 512 + k0 + schunk, As + r0 * 32 + lane * 8);
      async16(Bt + (size_t)(n0 + r0 + srow) * 512 + k0 + schunk, Bs + r0 * 32 + lane * 8);
    }
  };
  f32x4 acc[4][4] = {};
  stage(0, 0);
  for (int kt = 0; kt < 16; kt++) {
    int cur = kt & 1;
    __syncthreads();                 // buf[cur] prefetch (issued last iter) drained
    if (kt < 15) stage((kt + 1) * 32, cur ^ 1);
    unsigned short* As = (unsigned short*)(smem + cur * 16384);
    unsigned short* Bs = (unsigned short*)(smem + cur * 16384 + 8192);
    bf16x8 a[4], bb[4];
#pragma unroll
    for (int mt = 0; mt < 4; mt++)
      a[mt] = *(const bf16x8*)(As + (mrow + mt * 16 + l15) * 32 + quad * 8);
#pragma unroll
    for (int nt = 0; nt < 4; nt++)
      bb[nt] = *(const bf16x8*)(Bs + (ncol + nt * 16 + l15) * 32 + quad * 8);
#pragma unroll
    for (int mt = 0; mt < 4; mt++)
#pragma unroll
      for (int nt = 0; nt < 4; nt++)
        acc[mt][nt] = __builtin_amdgcn_mfma_f32_16x16x32_bf16(
            a[mt], bb[nt], acc[mt][nt], 0, 0, 0);
  }
  if (n0 < 1024) {
    float sc = ((n0 + ncol) < 512) ? S2L_ : 1.0f;   // pre-scale Q for exp2 softmax
#pragma unroll
    for (int mt = 0; mt < 4; mt++)
#pragma unroll
      for (int nt = 0; nt < 4; nt++)
#pragma unroll
        for (int r = 0; r < 4; r++) {
          int row = m0 + mrow + mt * 16 + quad * 4 + r;
          int col = n0 + ncol + nt * 16 + l15;
          out0[(size_t)row * 1024 + col] = f2bf((acc[mt][nt][r] + bias[col]) * sc);
        }
  } else {
    // V blocks: bf16 transposed into vt[(b*512 + (col-1024))*1024 + n]
    __syncthreads();
    unsigned short* buf = (unsigned short*)smem + wave * (64 * 17);
    int b = m0 >> 10, nbase = m0 & 1023;
    for (int nc = 0; nc < 4; nc++) {
#pragma unroll
      for (int mt = 0; mt < 4; mt++)
#pragma unroll
        for (int r = 0; r < 4; r++) {
          int col = n0 + ncol + nc * 16 + l15;
          buf[(mt * 16 + quad * 4 + r) * 17 + l15] = f2bf(acc[mt][nc][r] + bias[col]);
        }
      __syncthreads();
      for (int cc = 0; cc < 16; cc++) {
        int crel = n0 - 1024 + ncol + nc * 16 + cc;
        out1[((size_t)b * C_ + crel) * NSP + nbase + mrow + lane] = buf[lane * 17 + cc];
      }
      __syncthreads();
    }
  }
}

// ------------------------------------------------------------- proj GEMM
// out[b][c][n] fp32 = (A[M,512] @ Bt^T + bias)^T. 64x128 (MxN) tiles ->
// 512 blocks (2/CU). Single-barrier double-buffered K-loop as qkv.
__global__ __launch_bounds__(256) void gemm_proj_kernel(
    const unsigned short* __restrict__ A,
    const unsigned short* __restrict__ Bt,
    const float* __restrict__ bias,
    float* __restrict__ O) {
  __shared__ __align__(16) char smem[24576];   // [2] x (As 4K + Bs 8K)
  int tid = threadIdx.x;
  int wave = tid >> 6, lane = tid & 63, quad = lane >> 4, l15 = lane & 15;
  int n0 = blockIdx.x * 128, m0 = blockIdx.y * 64;
  int wm0 = (wave >> 1) * 32, wc0 = (wave & 1) * 64;
  int srow = lane >> 2, schunk = (lane & 3) * 8;
  auto stage = [&](int k0, int buf) {
    unsigned short* As = (unsigned short*)(smem + buf * 12288);
    unsigned short* Bs = (unsigned short*)(smem + buf * 12288 + 4096);
    async16(A + (size_t)(m0 + wave * 16 + srow) * 512 + k0 + schunk,
            As + (wave * 16) * 32 + lane * 8);
#pragma unroll
    for (int j = 0; j < 2; j++) {
      int r0 = (wave + 4 * j) * 16;
      async16(Bt + (size_t)(n0 + r0 + srow) * 512 + k0 + schunk, Bs + r0 * 32 + lane * 8);
    }
  };
  f32x4 acc[2][4] = {};
  stage(0, 0);
  for (int kt = 0; kt < 16; kt++) {
    int cur = kt & 1;
    __syncthreads();
    if (kt < 15) stage((kt + 1) * 32, cur ^ 1);
    unsigned short* As = (unsigned short*)(smem + cur * 12288);
    unsigned short* Bs = (unsigned short*)(smem + cur * 12288 + 4096);
    bf16x8 a[2], bb[4];
#pragma unroll
    for (int mt = 0; mt < 2; mt++)
      a[mt] = *(const bf16x8*)(As + (wm0 + mt * 16 + l15) * 32 + quad * 8);
#pragma unroll
    for (int nt = 0; nt < 4; nt++)
      bb[nt] = *(const bf16x8*)(Bs + (wc0 + nt * 16 + l15) * 32 + quad * 8);
#pragma unroll
    for (int mt = 0; mt < 2; mt++)
#pragma unroll
      for (int nt = 0; nt < 4; nt++)
        acc[mt][nt] = __builtin_amdgcn_mfma_f32_16x16x32_bf16(
            a[mt], bb[nt], acc[mt][nt], 0, 0, 0);
  }
  __syncthreads();                        // all waves done reading tiles
  float* buf = (float*)smem + wave * (32 * 17);   // [32][17] per wave
  int b = m0 >> 10, nbase = m0 & 1023;
  for (int nc = 0; nc < 4; nc++) {
#pragma unroll
    for (int mt = 0; mt < 2; mt++)
#pragma unroll
      for (int r = 0; r < 4; r++) {
        int col = n0 + wc0 + nc * 16 + l15;
        buf[(mt * 16 + quad * 4 + r) * 17 + l15] = acc[mt][nc][r] + bias[col];
      }
    // wave-private: ds_write->ds_read ordering handled by lgkmcnt, no barrier
#pragma unroll
    for (int j = 0; j < 8; j++) {
      int cl = j * 2 + (lane >> 5);       // 0..15 within nc group
      int ml = lane & 31;
      int c = n0 + wc0 + nc * 16 + cl;
      O[((size_t)b * C_ + c) * NSP + nbase + wm0 + ml] = buf[ml * 17 + cl];
    }
  }
}

// ------------------------------------------------------- flash attention
// R6-measured staging (async16 at iter top; NO register prefetch — R9's
// reg-prefetch spilled to scratch: WRITE_SIZE 8->170 MB).
// qk: [b*n][1024] bf16 (Q cols 0-511 PRE-SCALED by S2L_, K cols 512-1023);
// vt: [b*512+h*64+d][n]. block = (b,h, 64 q-rows), 4 waves:
//   qw = wave&1 (q-half, 32 rows), kh = wave>>1 (KEY-half, 512 keys).
// No-max exp2 softmax additive over keys -> key-parallel waves, in-block
// (O,l) combine. Tiles unpadded [64][64] + XOR chunk swizzle (conflict-free).
__global__ __launch_bounds__(256, 3) void attn_kernel(
    const unsigned short* __restrict__ qk,
    const unsigned short* __restrict__ vt,
    unsigned short* __restrict__ o_ws) {
  __shared__ __align__(16) unsigned short Ks[2][64][64];   // [kh][key][d]
  __shared__ __align__(16) unsigned short Vts[2][64][64];  // [kh][d][key]
  __shared__ __align__(16) unsigned short Ps[4][32][68];   // per-wave P[m][n]
  int tid = threadIdx.x;
  int wave = tid >> 6, lane = tid & 63, quad = lane >> 4, l15 = lane & 15;
  int qw = wave & 1, kh = wave >> 1;
  int b = blockIdx.x >> 3, h = blockIdx.x & 7;
  int q0 = blockIdx.y * 64 + qw * 32;
  int srow = lane >> 3, scc = lane & 7, swz = scc ^ srow;
  // ones A-fragment for l-sum MFMA: A[0][k]=1 else 0  (row = l15)
  uint4 ones4 = (l15 == 0) ? make_uint4(0x3F803F80u, 0x3F803F80u, 0x3F803F80u, 0x3F803F80u)
                           : make_uint4(0u, 0u, 0u, 0u);
  bf16x8 av5; __builtin_memcpy(&av5, &ones4, 16);
  // Q fragments straight from global (B-operand layout: rows m, k=d)
  bf16x8 bq[2][2];
#pragma unroll
  for (int mt = 0; mt < 2; mt++)
#pragma unroll
    for (int ks = 0; ks < 2; ks++)
      bq[mt][ks] = *(const bf16x8*)(
          qk + (size_t)(b * NSP + q0 + mt * 16 + l15) * 1024 +
          h * 64 + ks * 32 + quad * 8);
  f32x4 ot[4][2] = {};     // O^T partial: [d = dt*16+quad*4+r][m = mt*16+l15]
  f32x4 lacc[2] = {};      // l partial in lacc[mt][0] on quad==0 lanes
  for (int it = 0; it < 8; it++) {
    int k0 = kh * 512 + it * 64;
    __syncthreads();           // prev-iter readers done with this kh buffer
#pragma unroll
    for (int g = 0; g < 4; g++) {   // two qw waves stage complementary halves
      int row = qw * 32 + g * 8;
      async16(qk + (size_t)(b * NSP + k0 + row + srow) * 1024 + 512 + h * 64 + swz * 8,
              &Ks[kh][row][0]);
      async16(vt + ((size_t)(b * C_ + h * 64 + row + srow)) * NSP + k0 + swz * 8,
              &Vts[kh][row][0]);
    }
    __syncthreads();           // barrier drains async vmcnt; all waves staged
    // S^T[n][m] = mfma(A=K rows n, B=Q rows m)
    bf16x8 ak[4][2];
#pragma unroll
    for (int n4 = 0; n4 < 4; n4++)
#pragma unroll
      for (int ks = 0; ks < 2; ks++)
        ak[n4][ks] = *(const bf16x8*)(
            &Ks[kh][n4 * 16 + l15][((ks * 4 + quad) ^ (l15 & 7)) * 8]);
    f32x4 s[4][2] = {};
#pragma unroll
    for (int n4 = 0; n4 < 4; n4++)
#pragma unroll
      for (int mt = 0; mt < 2; mt++)
#pragma unroll
        for (int ks = 0; ks < 2; ks++)
          s[n4][mt] = __builtin_amdgcn_mfma_f32_16x16x32_bf16(
              ak[n4][ks], bq[mt][ks], s[n4][mt], 0, 0, 0);
    // P = exp2(S) (no max), packed cvt, wave-private LDS spill
#pragma unroll
    for (int mt = 0; mt < 2; mt++)
#pragma unroll
      for (int n4 = 0; n4 < 4; n4++) {
        float p0 = __builtin_amdgcn_exp2f(s[n4][mt][0]);
        float p1 = __builtin_amdgcn_exp2f(s[n4][mt][1]);
        float p2 = __builtin_amdgcn_exp2f(s[n4][mt][2]);
        float p3 = __builtin_amdgcn_exp2f(s[n4][mt][3]);
        *(uint2*)(&Ps[wave][mt * 16 + l15][n4 * 16 + quad * 4]) =
            make_uint2(pk2bf(p0, p1), pk2bf(p2, p3));
      }
    // O^T += mfma(A=V^T rows d, B=P rows m); l += ones-row MFMA
    bf16x8 av[4][2], bp[2][2];
#pragma unroll
    for (int dt = 0; dt < 4; dt++)
#pragma unroll
      for (int ks = 0; ks < 2; ks++)
        av[dt][ks] = *(const bf16x8*)(
            &Vts[kh][dt * 16 + l15][((ks * 4 + quad) ^ (l15 & 7)) * 8]);
#pragma unroll
    for (int mt = 0; mt < 2; mt++)
#pragma unroll
      for (int ks = 0; ks < 2; ks++)
        bp[mt][ks] = *(const bf16x8*)(&Ps[wave][mt * 16 + l15][ks * 32 + quad * 8]);
#pragma unroll
    for (int dt = 0; dt < 4; dt++)
#pragma unroll
      for (int mt = 0; mt < 2; mt++)
#pragma unroll
        for (int ks = 0; ks < 2; ks++)
          ot[dt][mt] = __builtin_amdgcn_mfma_f32_16x16x32_bf16(
              av[dt][ks], bp[mt][ks], ot[dt][mt], 0, 0, 0);
#pragma unroll
    for (int mt = 0; mt < 2; mt++)
#pragma unroll
      for (int ks = 0; ks < 2; ks++)
        lacc[mt] = __builtin_amdgcn_mfma_f32_16x16x32_bf16(
            av5, bp[mt][ks], lacc[mt], 0, 0, 0);
  }
  // in-block combine across key-halves (tiles dead -> alias as fp32 buffers)
  float* Cb = (float*)&Ks[0][0][0];   // [2][16][68] floats (qw, l15, d)
  float* Lb = (float*)&Vts[0][0][0];  // [2][16] floats
#pragma unroll
  for (int mt = 0; mt < 2; mt++) {
    __syncthreads();
    if (kh == 1) {
#pragma unroll
      for (int dt = 0; dt < 4; dt++)
        *(f32x4*)&Cb[(qw * 16 + l15) * 68 + dt * 16 + quad * 4] = ot[dt][mt];
      if (quad == 0) Lb[qw * 16 + l15] = lacc[mt][0];
    }
    __syncthreads();
    if (kh == 0) {
#pragma unroll
      for (int dt = 0; dt < 4; dt++)
        ot[dt][mt] += *(const f32x4*)&Cb[(qw * 16 + l15) * 68 + dt * 16 + quad * 4];
      float lsum = lacc[mt][0] + Lb[qw * 16 + l15];   // valid on quad==0
      float lv = __shfl(lsum, l15);                   // broadcast from quad0
      float inv = 1.f / lv;
      size_t rowoff = (size_t)(b * NSP + q0 + mt * 16 + l15) * 512 + h * 64;
#pragma unroll
      for (int dt = 0; dt < 4; dt++)
        *(uint2*)(o_ws + rowoff + dt * 16 + quad * 4) =
            make_uint2(pk2bf(ot[dt][mt][0] * inv, ot[dt][mt][1] * inv),
                       pk2bf(ot[dt][mt][2] * inv, ot[dt][mt][3] * inv));
    }
  }
}

// ------------------------------------------------------------------ launch
extern "C" void kernel_launch(void* const* d_in, const int* in_sizes, int n_in,
                              void* d_out, int out_size, void* d_ws, size_t ws_size,
                              hipStream_t stream) {
  const float* x     = (const float*)d_in[0];
  const float* gamma = (const float*)d_in[1];
  const float* beta  = (const float*)d_in[2];
  const float* wqkv  = (const float*)d_in[3];
  const float* bqkv  = (const float*)d_in[4];
  const float* wproj = (const float*)d_in[5];
  const float* bproj = (const float*)d_in[6];
  char* ws = (char*)d_ws;
  // workspace layout (~36 MB; o_bf aliases xn_bf — xn dead after QKV GEMM)
  float*          psum   = (float*)ws;                        // 128 KB [4][8192]
  float*          psum2  = (float*)(ws + 131072);             // 128 KB
  unsigned short* wqkvT  = (unsigned short*)(ws + 262144);    // 1.5 MB
  unsigned short* wprojT = (unsigned short*)(ws + 1835008);   // 0.5 MB
  unsigned short* qk_bf  = (unsigned short*)(ws + 2359296);   //  16 MB [m][1024]
  unsigned short* vt_bf  = (unsigned short*)(ws + 19136512);  //   8 MB [b*512+c][n]
  unsigned short* xn_bf  = (unsigned short*)(ws + 27525120);  //   8 MB
  unsigned short* o_bf   = xn_bf;                             //   8 MB (alias)
  float* out = (float*)d_out;

  ln_stats_kernel<<<1024, 256, 0, stream>>>(x, psum, psum2);
  applyw_kernel<<<1024 + 192 + 64, 256, 0, stream>>>(x, psum, psum2, gamma, beta,
                                                     wqkv, wproj, xn_bf, wqkvT, wprojT);
  gemm_qkv_kernel<<<dim3(NQKV / 128, M_ / 128), 256, 0, stream>>>(
      xn_bf, wqkvT, bqkv, qk_bf, vt_bf);
  attn_kernel<<<dim3(B_ * NH_, NSP / 64), 256, 0, stream>>>(qk_bf, vt_bf, o_bf);
  gemm_proj_kernel<<<dim3(C_ / 128, M_ / 64), 256, 0, stream>>>(
      o_bf, wprojT, bproj, out);
}

// Round 11
// 157.589 us; speedup vs baseline: 1.3353x; 1.0041x over previous
//
#include <hip/hip_runtime.h>
#include <hip/hip_bf16.h>
#include <math.h>

// Problem constants
#define B_   8
#define C_   512
#define NH_  8
#define HD_  64
#define NSP  1024            // H*W
#define M_   (B_*NSP)        // 8192 rows
#define NQKV 1536
#define SCALE_ 0.125f        // 1/sqrt(64)
#define S2L_  0.18033688f    // SCALE_ * log2(e)

typedef __attribute__((ext_vector_type(8))) __bf16 bf16x8;
typedef __attribute__((ext_vector_type(4))) float  f32x4;

__device__ __forceinline__ unsigned short f2bf(float f) {
  unsigned int u = __float_as_uint(f);
  u = u + 0x7fffu + ((u >> 16) & 1u);   // round-to-nearest-even
  return (unsigned short)(u >> 16);
}

// packed f32x2 -> bf16x2 (v_cvt_pk_bf16_f32 on gfx950); a -> low 16
__device__ __forceinline__ unsigned int pk2bf(float a, float b) {
  __hip_bfloat162 t = __float22bfloat162_rn(make_float2(a, b));
  unsigned int u; __builtin_memcpy(&u, &t, 4);
  return u;
}

// async global->LDS 16B (dest = wave-uniform base + lane*16)
__device__ __forceinline__ void async16(const unsigned short* g, unsigned short* l) {
  __builtin_amdgcn_global_load_lds(
      (const __attribute__((address_space(1))) void*)g,
      (__attribute__((address_space(3))) void*)l, 16, 0, 0);
}

// ------------------------------------------------ LN stats (partial sums)
// 1024 blocks = (b, n-chunk of 32, c-quarter); psum[cg][b*N+n], psum2 same.
__global__ void ln_stats_kernel(const float* __restrict__ x,
                                float* __restrict__ psum,
                                float* __restrict__ psum2) {
  int tx = threadIdx.x & 31, ty = threadIdx.x >> 5;
  int cg  = blockIdx.x & 3;
  int nch = (blockIdx.x >> 2) & 31;
  int b   = blockIdx.x >> 7;
  int n0 = nch * 32;
  const float* xp = x + (size_t)b * C_ * NSP + n0 + tx;
  float s = 0.f, s2 = 0.f;
  for (int c = cg * 128 + ty; c < cg * 128 + 128; c += 8) {
    float v = xp[(size_t)c * NSP];
    s += v; s2 += v * v;
  }
  __shared__ float sh_s[8][32], sh_s2[8][32];
  sh_s[ty][tx] = s; sh_s2[ty][tx] = s2;
  __syncthreads();
  if (ty == 0) {
    float S = 0.f, S2 = 0.f;
    for (int j = 0; j < 8; j++) { S += sh_s[j][tx]; S2 += sh_s2[j][tx]; }
    psum [cg * M_ + b * NSP + n0 + tx] = S;
    psum2[cg * M_ + b * NSP + n0 + tx] = S2;
  }
}

// --------------- LN apply+transpose (blocks 0..1023) + tiled weight convert
// blocks [0,1024):     apply (c0=(bx&7)*64, n0=((bx>>3)&15)*64, b=bx>>7)
// blocks [1024,1216):  wqkv 64x64 transpose tiles (8k x 24n)
// blocks [1216,1280):  wproj 64x64 transpose tiles (8k x 8n)
__global__ __launch_bounds__(256) void applyw_kernel(
    const float* __restrict__ x, const float* __restrict__ psum,
    const float* __restrict__ psum2, const float* __restrict__ gamma,
    const float* __restrict__ beta, const float* __restrict__ wqkv,
    const float* __restrict__ wproj, unsigned short* __restrict__ xn,
    unsigned short* __restrict__ wqkvT, unsigned short* __restrict__ wprojT) {
  int tid = threadIdx.x;
  __shared__ float tile[64][65];
  int tx = tid & 63, ty = tid >> 6;
  if (blockIdx.x >= 1024) {
    // weight transpose via LDS bounce: in [k][n] fp32 -> out [n][k] bf16
    const float* W; unsigned short* WT; int NW, t;
    if (blockIdx.x < 1216) { W = wqkv;  WT = wqkvT;  NW = NQKV; t = blockIdx.x - 1024; }
    else                   { W = wproj; WT = wprojT; NW = C_;   t = blockIdx.x - 1216; }
    int ntiles = NW >> 6;
    int kt = t / ntiles, nt = t - kt * ntiles;
    for (int i = ty; i < 64; i += 4)                      // read coalesced in n
      tile[i][tx] = W[(size_t)(kt * 64 + i) * NW + nt * 64 + tx];
    __syncthreads();
    for (int i = ty; i < 64; i += 4)                      // write rows of WT
      WT[(size_t)(nt * 64 + i) * C_ + kt * 64 + tx] = f2bf(tile[tx][i]);
    return;
  }
  __shared__ float smu[64], srs[64];
  int c0 = (blockIdx.x & 7) * 64;
  int n0 = ((blockIdx.x >> 3) & 15) * 64;
  int b  = blockIdx.x >> 7;
  if (tid < 64) {                       // reduce 4 partials -> mu, rstd
    int n = b * NSP + n0 + tid;
    float s  = psum [n] + psum [M_ + n] + psum [2 * M_ + n] + psum [3 * M_ + n];
    float s2 = psum2[n] + psum2[M_ + n] + psum2[2 * M_ + n] + psum2[3 * M_ + n];
    float mu = s * (1.0f / C_);
    float var = s2 * (1.0f / C_) - mu * mu;
    smu[tid] = mu;
    srs[tid] = rsqrtf(var + 1e-5f);
  }
  const float* xp = x + ((size_t)b * C_ + c0) * NSP + n0;
  for (int i = ty; i < 64; i += 4)
    tile[i][tx] = xp[(size_t)i * NSP + tx];           // tile[c][n], coalesced
  __syncthreads();
  float g = gamma[c0 + tx], be = beta[c0 + tx];       // tx = c-offset now
  unsigned short* op = xn + ((size_t)(b * NSP + n0)) * C_ + c0 + tx;
  for (int i = ty; i < 64; i += 4) {                  // i = n-offset
    float v = (tile[tx][i] - smu[i]) * srs[i] * g + be;
    op[(size_t)i * C_] = f2bf(v);                     // coalesced bf16 write
  }
}

// ------------------------------------------------------------- QKV GEMM
// C[M,1536] = A[M,512] @ B + bias. 64x128 (MxN) tiles -> 1536 blocks
// (6/CU, LDS-cap also 6 at 24 KB dbuf -> 24 waves/CU; was 3 blocks/12 waves).
// Single-barrier double-buffered K-loop, global_load_lds width-16.
// col<512 -> Q scaled by S2L_; col in [512,1024) -> K; both bf16 stride 1024.
// col>=1024 -> V bf16 transposed into out1 = vt[(b*512+c-1024)*1024+n]
__global__ __launch_bounds__(256) void gemm_qkv_kernel(
    const unsigned short* __restrict__ A,
    const unsigned short* __restrict__ Bt,
    const float* __restrict__ bias,
    unsigned short* __restrict__ out0, unsigned short* __restrict__ out1) {
  __shared__ __align__(16) char smem[24576];   // [2] x (As 4K + Bs 8K)
  int tid = threadIdx.x;
  int wave = tid >> 6, lane = tid & 63, quad = lane >> 4, l15 = lane & 15;
  int n0 = blockIdx.x * 128, m0 = blockIdx.y * 64;
  int wm = (wave >> 1) * 32, wn = (wave & 1) * 64;
  int srow = lane >> 2, schunk = (lane & 3) * 8;
  auto stage = [&](int k0, int buf) {
    unsigned short* As = (unsigned short*)(smem + buf * 12288);
    unsigned short* Bs = (unsigned short*)(smem + buf * 12288 + 4096);
    async16(A + (size_t)(m0 + wave * 16 + srow) * 512 + k0 + schunk,
            As + wave * 16 * 32 + lane * 8);
#pragma unroll
    for (int j = 0; j < 2; j++) {
      int r0 = (wave + 4 * j) * 16;
      async16(Bt + (size_t)(n0 + r0 + srow) * 512 + k0 + schunk, Bs + r0 * 32 + lane * 8);
    }
  };
  f32x4 acc[2][4] = {};
  stage(0, 0);
  for (int kt = 0; kt < 16; kt++) {
    int cur = kt & 1;
    __syncthreads();                 // buf[cur] prefetch (issued last iter) drained
    if (kt < 15) stage((kt + 1) * 32, cur ^ 1);
    unsigned short* As = (unsigned short*)(smem + cur * 12288);
    unsigned short* Bs = (unsigned short*)(smem + cur * 12288 + 4096);
    bf16x8 a[2], bb[4];
#pragma unroll
    for (int mt = 0; mt < 2; mt++)
      a[mt] = *(const bf16x8*)(As + (wm + mt * 16 + l15) * 32 + quad * 8);
#pragma unroll
    for (int nt = 0; nt < 4; nt++)
      bb[nt] = *(const bf16x8*)(Bs + (wn + nt * 16 + l15) * 32 + quad * 8);
#pragma unroll
    for (int mt = 0; mt < 2; mt++)
#pragma unroll
      for (int nt = 0; nt < 4; nt++)
        acc[mt][nt] = __builtin_amdgcn_mfma_f32_16x16x32_bf16(
            a[mt], bb[nt], acc[mt][nt], 0, 0, 0);
  }
  if (n0 < 1024) {
    float sc = ((n0 + wn) < 512) ? S2L_ : 1.0f;   // pre-scale Q for exp2 softmax
#pragma unroll
    for (int mt = 0; mt < 2; mt++)
#pragma unroll
      for (int nt = 0; nt < 4; nt++)
#pragma unroll
        for (int r = 0; r < 4; r++) {
          int row = m0 + wm + mt * 16 + quad * 4 + r;
          int col = n0 + wn + nt * 16 + l15;
          out0[(size_t)row * 1024 + col] = f2bf((acc[mt][nt][r] + bias[col]) * sc);
        }
  } else {
    // V blocks: bf16 transposed into vt[(b*512 + (col-1024))*1024 + n]
    __syncthreads();                  // all waves done reading tiles
    unsigned short* buf = (unsigned short*)smem + wave * (32 * 17);  // [32][17]
    int b = m0 >> 10, nbase = m0 & 1023;
    for (int nc = 0; nc < 4; nc++) {
#pragma unroll
      for (int mt = 0; mt < 2; mt++)
#pragma unroll
        for (int r = 0; r < 4; r++) {
          int col = n0 + wn + nc * 16 + l15;
          buf[(mt * 16 + quad * 4 + r) * 17 + l15] = f2bf(acc[mt][nc][r] + bias[col]);
        }
      // wave-private buffer: ds ordering via lgkmcnt, no barrier needed
      int ml = lane & 31;
#pragma unroll
      for (int j = 0; j < 8; j++) {
        int cl = j * 2 + (lane >> 5);
        int crel = n0 - 1024 + wn + nc * 16 + cl;
        out1[((size_t)b * C_ + crel) * NSP + nbase + wm + ml] = buf[ml * 17 + cl];
      }
    }
  }
}

// ------------------------------------------------------------- proj GEMM
// out[b][c][n] fp32 = (A[M,512] @ Bt^T + bias)^T. 32x128 (MxN) tiles ->
// 1024 blocks (4/CU, 16 waves/CU; was 512 = 2/CU grid-capped).
// Single-barrier double-buffered K-loop.
__global__ __launch_bounds__(256) void gemm_proj_kernel(
    const unsigned short* __restrict__ A,
    const unsigned short* __restrict__ Bt,
    const float* __restrict__ bias,
    float* __restrict__ O) {
  __shared__ __align__(16) char smem[20480];   // [2] x (As 2K + Bs 8K)
  int tid = threadIdx.x;
  int wave = tid >> 6, lane = tid & 63, quad = lane >> 4, l15 = lane & 15;
  int n0 = blockIdx.x * 128, m0 = blockIdx.y * 32;
  int wm = (wave >> 1) * 16, wn = (wave & 1) * 64;
  int srow = lane >> 2, schunk = (lane & 3) * 8;
  auto stage = [&](int k0, int buf) {
    unsigned short* As = (unsigned short*)(smem + buf * 10240);
    unsigned short* Bs = (unsigned short*)(smem + buf * 10240 + 2048);
    if (wave < 2)
      async16(A + (size_t)(m0 + wave * 16 + srow) * 512 + k0 + schunk,
              As + wave * 16 * 32 + lane * 8);
#pragma unroll
    for (int j = 0; j < 2; j++) {
      int r0 = (wave + 4 * j) * 16;
      async16(Bt + (size_t)(n0 + r0 + srow) * 512 + k0 + schunk, Bs + r0 * 32 + lane * 8);
    }
  };
  f32x4 acc[4] = {};
  stage(0, 0);
  for (int kt = 0; kt < 16; kt++) {
    int cur = kt & 1;
    __syncthreads();
    if (kt < 15) stage((kt + 1) * 32, cur ^ 1);
    unsigned short* As = (unsigned short*)(smem + cur * 10240);
    unsigned short* Bs = (unsigned short*)(smem + cur * 10240 + 2048);
    bf16x8 a, bb[4];
    a = *(const bf16x8*)(As + (wm + l15) * 32 + quad * 8);
#pragma unroll
    for (int nt = 0; nt < 4; nt++)
      bb[nt] = *(const bf16x8*)(Bs + (wn + nt * 16 + l15) * 32 + quad * 8);
#pragma unroll
    for (int nt = 0; nt < 4; nt++)
      acc[nt] = __builtin_amdgcn_mfma_f32_16x16x32_bf16(a, bb[nt], acc[nt], 0, 0, 0);
  }
  __syncthreads();                        // all waves done reading tiles
  float* buf = (float*)smem + wave * (16 * 17);   // [16][17] per wave
  int b = m0 >> 10, nbase = m0 & 1023;
  int ml = lane & 15, cg = lane >> 4;
  for (int nc = 0; nc < 4; nc++) {
#pragma unroll
    for (int r = 0; r < 4; r++) {
      int col = n0 + wn + nc * 16 + l15;
      buf[(quad * 4 + r) * 17 + l15] = acc[nc][r] + bias[col];
    }
    // wave-private: ds_write->ds_read ordering by lgkmcnt, no barrier
#pragma unroll
    for (int j = 0; j < 4; j++) {
      int cl = j * 4 + cg;
      int c = n0 + wn + nc * 16 + cl;
      O[((size_t)b * C_ + c) * NSP + nbase + wm + ml] = buf[ml * 17 + cl];
    }
  }
}

// ------------------------------------------------------- flash attention
// R6-measured staging (async16 at iter top; NO register prefetch — R9's
// reg-prefetch spilled to scratch: WRITE_SIZE 8->170 MB).
// qk: [b*n][1024] bf16 (Q cols 0-511 PRE-SCALED by S2L_, K cols 512-1023);
// vt: [b*512+h*64+d][n]. block = (b,h, 64 q-rows), 4 waves:
//   qw = wave&1 (q-half, 32 rows), kh = wave>>1 (KEY-half, 512 keys).
// No-max exp2 softmax additive over keys -> key-parallel waves, in-block
// (O,l) combine. Tiles unpadded [64][64] + XOR chunk swizzle (conflict-free).
__global__ __launch_bounds__(256, 3) void attn_kernel(
    const unsigned short* __restrict__ qk,
    const unsigned short* __restrict__ vt,
    unsigned short* __restrict__ o_ws) {
  __shared__ __align__(16) unsigned short Ks[2][64][64];   // [kh][key][d]
  __shared__ __align__(16) unsigned short Vts[2][64][64];  // [kh][d][key]
  __shared__ __align__(16) unsigned short Ps[4][32][68];   // per-wave P[m][n]
  int tid = threadIdx.x;
  int wave = tid >> 6, lane = tid & 63, quad = lane >> 4, l15 = lane & 15;
  int qw = wave & 1, kh = wave >> 1;
  int b = blockIdx.x >> 3, h = blockIdx.x & 7;
  int q0 = blockIdx.y * 64 + qw * 32;
  int srow = lane >> 3, scc = lane & 7, swz = scc ^ srow;
  // ones A-fragment for l-sum MFMA: A[0][k]=1 else 0  (row = l15)
  uint4 ones4 = (l15 == 0) ? make_uint4(0x3F803F80u, 0x3F803F80u, 0x3F803F80u, 0x3F803F80u)
                           : make_uint4(0u, 0u, 0u, 0u);
  bf16x8 av5; __builtin_memcpy(&av5, &ones4, 16);
  // Q fragments straight from global (B-operand layout: rows m, k=d)
  bf16x8 bq[2][2];
#pragma unroll
  for (int mt = 0; mt < 2; mt++)
#pragma unroll
    for (int ks = 0; ks < 2; ks++)
      bq[mt][ks] = *(const bf16x8*)(
          qk + (size_t)(b * NSP + q0 + mt * 16 + l15) * 1024 +
          h * 64 + ks * 32 + quad * 8);
  f32x4 ot[4][2] = {};     // O^T partial: [d = dt*16+quad*4+r][m = mt*16+l15]
  f32x4 lacc[2] = {};      // l partial in lacc[mt][0] on quad==0 lanes
  for (int it = 0; it < 8; it++) {
    int k0 = kh * 512 + it * 64;
    __syncthreads();           // prev-iter readers done with this kh buffer
#pragma unroll
    for (int g = 0; g < 4; g++) {   // two qw waves stage complementary halves
      int row = qw * 32 + g * 8;
      async16(qk + (size_t)(b * NSP + k0 + row + srow) * 1024 + 512 + h * 64 + swz * 8,
              &Ks[kh][row][0]);
      async16(vt + ((size_t)(b * C_ + h * 64 + row + srow)) * NSP + k0 + swz * 8,
              &Vts[kh][row][0]);
    }
    __syncthreads();           // barrier drains async vmcnt; all waves staged
    // S^T[n][m] = mfma(A=K rows n, B=Q rows m)
    bf16x8 ak[4][2];
#pragma unroll
    for (int n4 = 0; n4 < 4; n4++)
#pragma unroll
      for (int ks = 0; ks < 2; ks++)
        ak[n4][ks] = *(const bf16x8*)(
            &Ks[kh][n4 * 16 + l15][((ks * 4 + quad) ^ (l15 & 7)) * 8]);
    f32x4 s[4][2] = {};
#pragma unroll
    for (int n4 = 0; n4 < 4; n4++)
#pragma unroll
      for (int mt = 0; mt < 2; mt++)
#pragma unroll
        for (int ks = 0; ks < 2; ks++)
          s[n4][mt] = __builtin_amdgcn_mfma_f32_16x16x32_bf16(
              ak[n4][ks], bq[mt][ks], s[n4][mt], 0, 0, 0);
    // P = exp2(S) (no max), packed cvt, wave-private LDS spill
#pragma unroll
    for (int mt = 0; mt < 2; mt++)
#pragma unroll
      for (int n4 = 0; n4 < 4; n4++) {
        float p0 = __builtin_amdgcn_exp2f(s[n4][mt][0]);
        float p1 = __builtin_amdgcn_exp2f(s[n4][mt][1]);
        float p2 = __builtin_amdgcn_exp2f(s[n4][mt][2]);
        float p3 = __builtin_amdgcn_exp2f(s[n4][mt][3]);
        *(uint2*)(&Ps[wave][mt * 16 + l15][n4 * 16 + quad * 4]) =
            make_uint2(pk2bf(p0, p1), pk2bf(p2, p3));
      }
    // O^T += mfma(A=V^T rows d, B=P rows m); l += ones-row MFMA
    bf16x8 av[4][2], bp[2][2];
#pragma unroll
    for (int dt = 0; dt < 4; dt++)
#pragma unroll
      for (int ks = 0; ks < 2; ks++)
        av[dt][ks] = *(const bf16x8*)(
            &Vts[kh][dt * 16 + l15][((ks * 4 + quad) ^ (l15 & 7)) * 8]);
#pragma unroll
    for (int mt = 0; mt < 2; mt++)
#pragma unroll
      for (int ks = 0; ks < 2; ks++)
        bp[mt][ks] = *(const bf16x8*)(&Ps[wave][mt * 16 + l15][ks * 32 + quad * 8]);
#pragma unroll
    for (int dt = 0; dt < 4; dt++)
#pragma unroll
      for (int mt = 0; mt < 2; mt++)
#pragma unroll
        for (int ks = 0; ks < 2; ks++)
          ot[dt][mt] = __builtin_amdgcn_mfma_f32_16x16x32_bf16(
              av[dt][ks], bp[mt][ks], ot[dt][mt], 0, 0, 0);
#pragma unroll
    for (int mt = 0; mt < 2; mt++)
#pragma unroll
      for (int ks = 0; ks < 2; ks++)
        lacc[mt] = __builtin_amdgcn_mfma_f32_16x16x32_bf16(
            av5, bp[mt][ks], lacc[mt], 0, 0, 0);
  }
  // in-block combine across key-halves (tiles dead -> alias as fp32 buffers)
  float* Cb = (float*)&Ks[0][0][0];   // [2][16][68] floats (qw, l15, d)
  float* Lb = (float*)&Vts[0][0][0];  // [2][16] floats
#pragma unroll
  for (int mt = 0; mt < 2; mt++) {
    __syncthreads();
    if (kh == 1) {
#pragma unroll
      for (int dt = 0; dt < 4; dt++)
        *(f32x4*)&Cb[(qw * 16 + l15) * 68 + dt * 16 + quad * 4] = ot[dt][mt];
      if (quad == 0) Lb[qw * 16 + l15] = lacc[mt][0];
    }
    __syncthreads();
    if (kh == 0) {
#pragma unroll
      for (int dt = 0; dt < 4; dt++)
        ot[dt][mt] += *(const f32x4*)&Cb[(qw * 16 + l15) * 68 + dt * 16 + quad * 4];
      float lsum = lacc[mt][0] + Lb[qw * 16 + l15];   // valid on quad==0
      float lv = __shfl(lsum, l15);                   // broadcast from quad0
      float inv = 1.f / lv;
      size_t rowoff = (size_t)(b * NSP + q0 + mt * 16 + l15) * 512 + h * 64;
#pragma unroll
      for (int dt = 0; dt < 4; dt++)
        *(uint2*)(o_ws + rowoff + dt * 16 + quad * 4) =
            make_uint2(pk2bf(ot[dt][mt][0] * inv, ot[dt][mt][1] * inv),
                       pk2bf(ot[dt][mt][2] * inv, ot[dt][mt][3] * inv));
    }
  }
}

// ------------------------------------------------------------------ launch
extern "C" void kernel_launch(void* const* d_in, const int* in_sizes, int n_in,
                              void* d_out, int out_size, void* d_ws, size_t ws_size,
                              hipStream_t stream) {
  const float* x     = (const float*)d_in[0];
  const float* gamma = (const float*)d_in[1];
  const float* beta  = (const float*)d_in[2];
  const float* wqkv  = (const float*)d_in[3];
  const float* bqkv  = (const float*)d_in[4];
  const float* wproj = (const float*)d_in[5];
  const float* bproj = (const float*)d_in[6];
  char* ws = (char*)d_ws;
  // workspace layout (~36 MB; o_bf aliases xn_bf — xn dead after QKV GEMM)
  float*          psum   = (float*)ws;                        // 128 KB [4][8192]
  float*          psum2  = (float*)(ws + 131072);             // 128 KB
  unsigned short* wqkvT  = (unsigned short*)(ws + 262144);    // 1.5 MB
  unsigned short* wprojT = (unsigned short*)(ws + 1835008);   // 0.5 MB
  unsigned short* qk_bf  = (unsigned short*)(ws + 2359296);   //  16 MB [m][1024]
  unsigned short* vt_bf  = (unsigned short*)(ws + 19136512);  //   8 MB [b*512+c][n]
  unsigned short* xn_bf  = (unsigned short*)(ws + 27525120);  //   8 MB
  unsigned short* o_bf   = xn_bf;                             //   8 MB (alias)
  float* out = (float*)d_out;

  ln_stats_kernel<<<1024, 256, 0, stream>>>(x, psum, psum2);
  applyw_kernel<<<1024 + 192 + 64, 256, 0, stream>>>(x, psum, psum2, gamma, beta,
                                                     wqkv, wproj, xn_bf, wqkvT, wprojT);
  gemm_qkv_kernel<<<dim3(NQKV / 128, M_ / 64), 256, 0, stream>>>(
      xn_bf, wqkvT, bqkv, qk_bf, vt_bf);
  attn_kernel<<<dim3(B_ * NH_, NSP / 64), 256, 0, stream>>>(qk_bf, vt_bf, o_bf);
  gemm_proj_kernel<<<dim3(C_ / 128, M_ / 32), 256, 0, stream>>>(
      o_bf, wprojT, bproj, out);
}